// Round 1
// baseline (190.112 us; speedup 1.0000x reference)
//
#include <hip/hip_runtime.h>

typedef __bf16 bf16x8 __attribute__((ext_vector_type(8)));
typedef float f32x4 __attribute__((ext_vector_type(4)));

constexpr int N_ = 16384;
constexpr int D_ = 16;
constexpr int P_ = 8;
constexpr int H_ = 128;
constexpr int M_ = 50;
constexpr int A0S = 40;   // A0 row stride (bf16 elems): 32 used + 8 pad (80B, 16B-aligned)
constexpr int HS  = 144;  // h row stride: 128 used + 16 pad (288B, conflict-free writes)

__global__ __launch_bounds__(64, 1)
void sde_fused(const float* __restrict__ X0,
               const float* __restrict__ V0,
               const float* __restrict__ Yobs,
               const float* __restrict__ noise,
               const float* __restrict__ W1, const float* __restrict__ b1,
               const float* __restrict__ W2, const float* __restrict__ b2,
               const float* __restrict__ W3, const float* __restrict__ b3,
               float* __restrict__ out)
{
    // Single wave per block: all LDS slices are wave-private -> no barriers in loop.
    __shared__ __bf16 A0[16 * A0S];  // cols 0..15 = X, 16..23 = Y, 24..31 = 0
    __shared__ __bf16 H1[16 * HS];
    __shared__ __bf16 H2[16 * HS];

    const int lane = threadIdx.x;   // 0..63
    const int col  = lane & 15;
    const int q    = lane >> 4;
    const int row0 = blockIdx.x * 16;

    const float dt   = (float)(1.0 / 50.0);
    const float sqdt = sqrtf((float)(1.0 / 50.0));

    // ---- weight fragments in registers (MFMA B layout: B[k][n], n=col, k=q*8+j) ----
    bf16x8 w1f[8];      // [ct] : W1 rows 1..24 (t folded into bias), zero-padded K to 32
    bf16x8 w2f[8][4];   // [ct][kt]
    bf16x8 w3f[4];      // [kt]

#pragma unroll
    for (int ct = 0; ct < 8; ++ct) {
        bf16x8 f;
#pragma unroll
        for (int j = 0; j < 8; ++j) {
            int k = q * 8 + j;
            f[j] = (k < 24) ? (__bf16)W1[(1 + k) * H_ + ct * 16 + col] : (__bf16)0.0f;
        }
        w1f[ct] = f;
    }
#pragma unroll
    for (int ct = 0; ct < 8; ++ct) {
#pragma unroll
        for (int kt = 0; kt < 4; ++kt) {
            bf16x8 f;
#pragma unroll
            for (int j = 0; j < 8; ++j)
                f[j] = (__bf16)W2[(kt * 32 + q * 8 + j) * H_ + ct * 16 + col];
            w2f[ct][kt] = f;
        }
    }
#pragma unroll
    for (int kt = 0; kt < 4; ++kt) {
        bf16x8 f;
#pragma unroll
        for (int j = 0; j < 8; ++j)
            f[j] = (__bf16)W3[(kt * 32 + q * 8 + j) * D_ + col];
        w3f[kt] = f;
    }

    // biases per lane (C/D layout: bias depends only on output col)
    float b1e[8], dtw1[8], b2r[8];
#pragma unroll
    for (int ct = 0; ct < 8; ++ct) {
        b1e[ct]  = b1[ct * 16 + col];           // t=0 at step 0
        dtw1[ct] = dt * W1[ct * 16 + col];      // dt * W1[0,:]  (time-column fold)
        b2r[ct]  = b2[ct * 16 + col];
    }
    float b3r = b3[col];

    // ---- state (C/D layout: lane holds rows q*4+r, column `col`) ----
    float x[4], v[4];
#pragma unroll
    for (int r = 0; r < 4; ++r) {
        int gr = row0 + q * 4 + r;
        x[r] = X0[gr * D_ + col];
        v[r] = V0[gr];     // replicated across the 16 lanes of the q-group
    }

    // ---- static part of A0: Y in cols 16..23, zeros in 24..31 (row index = col field) ----
    {
        int r  = col;
        int gr = row0 + r;
        if (q < 2) {
#pragma unroll
            for (int p = 0; p < 4; ++p)
                A0[r * A0S + 16 + q * 4 + p] = (__bf16)Yobs[gr * P_ + q * 4 + p];
        } else {
#pragma unroll
            for (int p = 0; p < 4; ++p)
                A0[r * A0S + 24 + (q - 2) * 4 + p] = (__bf16)0.0f;
        }
    }
    // X_0 into A0 cols 0..15
#pragma unroll
    for (int r = 0; r < 4; ++r)
        A0[(q * 4 + r) * A0S + col] = (__bf16)x[r];

    __syncthreads();

    // noise for step 0; prefetch pipeline one step ahead
    float ecur[4], enext[4];
    {
        const float* p = noise + (size_t)row0 * D_;
#pragma unroll
        for (int r = 0; r < 4; ++r) ecur[r] = p[(q * 4 + r) * D_ + col];
    }

    for (int m = 0; m < M_; ++m) {
        // ---- layer 1: h1 = relu([X|Y] @ W1[1:] + (b1 + t*W1[0])) ----
        bf16x8 a0f = *(const bf16x8*)&A0[col * A0S + q * 8];
#pragma unroll
        for (int ct = 0; ct < 8; ++ct) {
            f32x4 c = { b1e[ct], b1e[ct], b1e[ct], b1e[ct] };
            c = __builtin_amdgcn_mfma_f32_16x16x32_bf16(a0f, w1f[ct], c, 0, 0, 0);
#pragma unroll
            for (int r = 0; r < 4; ++r)
                H1[(q * 4 + r) * HS + ct * 16 + col] = (__bf16)fmaxf(c[r], 0.0f);
        }
        // ---- layer 2: h2 = relu(h1 @ W2 + b2) ----
        bf16x8 h1f[4];
#pragma unroll
        for (int kt = 0; kt < 4; ++kt)
            h1f[kt] = *(const bf16x8*)&H1[col * HS + kt * 32 + q * 8];
#pragma unroll
        for (int ct = 0; ct < 8; ++ct) {
            f32x4 c = { b2r[ct], b2r[ct], b2r[ct], b2r[ct] };
#pragma unroll
            for (int kt = 0; kt < 4; ++kt)
                c = __builtin_amdgcn_mfma_f32_16x16x32_bf16(h1f[kt], w2f[ct][kt], c, 0, 0, 0);
#pragma unroll
            for (int r = 0; r < 4; ++r)
                H2[(q * 4 + r) * HS + ct * 16 + col] = (__bf16)fmaxf(c[r], 0.0f);
        }
        // ---- prefetch next-step noise (consumed next iteration; ~1 step of latency cover) ----
        if (m + 1 < M_) {
            const float* p = noise + ((size_t)(m + 1) * N_ + row0) * D_;
#pragma unroll
            for (int r = 0; r < 4; ++r) enext[r] = p[(q * 4 + r) * D_ + col];
        }
        // ---- layer 3: Z = h2 @ W3 + b3 (output already in C/D layout = per-row layout) ----
        bf16x8 h2f[4];
#pragma unroll
        for (int kt = 0; kt < 4; ++kt)
            h2f[kt] = *(const bf16x8*)&H2[col * HS + kt * 32 + q * 8];
        f32x4 z = { b3r, b3r, b3r, b3r };
#pragma unroll
        for (int kt = 0; kt < 4; ++kt)
            z = __builtin_amdgcn_mfma_f32_16x16x32_bf16(h2f[kt], w3f[kt], z, 0, 0, 0);

        // ---- V, X update (fp32; reduce over the 16 cols via shfl_xor in-group) ----
#pragma unroll
        for (int r = 0; r < 4; ++r) {
            float wn = sqdt * ecur[r];
            float t  = z[r] * wn + 0.5f * dt * z[r] * z[r];
            t += __shfl_xor(t, 1);
            t += __shfl_xor(t, 2);
            t += __shfl_xor(t, 4);
            t += __shfl_xor(t, 8);
            v[r] += t;
            x[r] = x[r] * (1.0f - dt) + wn;   // X = X - dt*X + sigma*Wn
        }
#pragma unroll
        for (int r = 0; r < 4; ++r) ecur[r] = enext[r];
        // write X_{m+1} into A0 for next step's layer-1 read
#pragma unroll
        for (int r = 0; r < 4; ++r)
            A0[(q * 4 + r) * A0S + col] = (__bf16)x[r];
        // advance time-folded bias: t += dt
#pragma unroll
        for (int ct = 0; ct < 8; ++ct) b1e[ct] += dtw1[ct];
    }

    // ---- store: X (N x 16) then V (N), concatenated ----
#pragma unroll
    for (int r = 0; r < 4; ++r) {
        int gr = row0 + q * 4 + r;
        out[gr * D_ + col] = x[r];
        if (col == 0) out[N_ * D_ + gr] = v[r];
    }
}

extern "C" void kernel_launch(void* const* d_in, const int* in_sizes, int n_in,
                              void* d_out, int out_size, void* d_ws, size_t ws_size,
                              hipStream_t stream)
{
    const float* X0 = (const float*)d_in[0];
    const float* V0 = (const float*)d_in[1];
    const float* Y  = (const float*)d_in[2];
    const float* nz = (const float*)d_in[3];
    const float* W1 = (const float*)d_in[4];
    const float* b1 = (const float*)d_in[5];
    const float* W2 = (const float*)d_in[6];
    const float* b2 = (const float*)d_in[7];
    const float* W3 = (const float*)d_in[8];
    const float* b3 = (const float*)d_in[9];
    float* out = (float*)d_out;

    sde_fused<<<N_ / 16, 64, 0, stream>>>(X0, V0, Y, nz, W1, b1, W2, b2, W3, b3, out);
}

// Round 2
// 142.110 us; speedup vs baseline: 1.3378x; 1.3378x over previous
//
#include <hip/hip_runtime.h>

typedef __bf16 bf16x8 __attribute__((ext_vector_type(8)));
typedef float  f32x4  __attribute__((ext_vector_type(4)));
typedef float  f32x2  __attribute__((ext_vector_type(2)));

constexpr int N_ = 16384;
constexpr int D_ = 16;
constexpr int P_ = 8;
constexpr int H_ = 128;
constexpr int M_ = 50;

// Fully transposed, register-resident formulation. Per 16-particle tile (one
// wave): h^T = W^T @ act^T for every layer, so each MFMA's C/D output (lane:
// col=lane&15 -> particle, rows q*4+r -> feature subset) is directly the B
// operand of the next MFMA under the contraction-index permutation
//   pi(kt,q,j) = (kt*2 + (j>>2))*16 + q*4 + (j&3)
// which we bake into the (register-resident, loaded-once) weight fragments.
// => zero LDS, zero barriers inside the 50-step loop.
__global__ __launch_bounds__(64, 1)
void sde_fused(const float* __restrict__ X0,
               const float* __restrict__ V0,
               const float* __restrict__ Yobs,
               const float* __restrict__ noise,
               const float* __restrict__ W1, const float* __restrict__ b1,
               const float* __restrict__ W2, const float* __restrict__ b2,
               const float* __restrict__ W3, const float* __restrict__ b3,
               float* __restrict__ out)
{
    const int lane = threadIdx.x;   // 0..63
    const int n    = lane & 15;     // particle index within tile
    const int q    = lane >> 4;     // quad
    const int gr   = blockIdx.x * 16 + n;

    const float dt   = 0.02f;
    const float sqdt = 0.1414213562373095f;   // sqrt(0.02)

    // ---- weight fragments, A-operand layout A[m=lane&15][k=q*8+j] ----
    // layer 1 (K=32): k slots j=0..3 -> X feature q*4+j (W1 row 1+q*4+j)
    //                 j=4,5 -> Y feature q*2+(j-4)     (W1 row 17+q*2+(j-4))
    //                 j=6   -> bias row (only q==0)    (b1)
    //                 j=7   -> time row (only q==0)    (W1 row 0)
    bf16x8 w1f[8];
#pragma unroll
    for (int ct = 0; ct < 8; ++ct) {
        bf16x8 f;
#pragma unroll
        for (int j = 0; j < 4; ++j)
            f[j] = (__bf16)W1[(1 + q * 4 + j) * H_ + ct * 16 + n];
#pragma unroll
        for (int j = 4; j < 6; ++j)
            f[j] = (__bf16)W1[(17 + q * 2 + (j - 4)) * H_ + ct * 16 + n];
        f[6] = (q == 0) ? (__bf16)b1[ct * 16 + n] : (__bf16)0.0f;
        f[7] = (q == 0) ? (__bf16)W1[ct * 16 + n] : (__bf16)0.0f;
        w1f[ct] = f;
    }
    // layers 2,3 (K=128): k = pi(kt,q,j)
    bf16x8 w2f[8][4];
#pragma unroll
    for (int ct = 0; ct < 8; ++ct)
#pragma unroll
        for (int kt = 0; kt < 4; ++kt) {
            bf16x8 f;
#pragma unroll
            for (int j = 0; j < 8; ++j) {
                int h = (kt * 2 + (j >> 2)) * 16 + q * 4 + (j & 3);
                f[j] = (__bf16)W2[h * H_ + ct * 16 + n];
            }
            w2f[ct][kt] = f;
        }
    bf16x8 w3f[4];
#pragma unroll
    for (int kt = 0; kt < 4; ++kt) {
        bf16x8 f;
#pragma unroll
        for (int j = 0; j < 8; ++j) {
            int h = (kt * 2 + (j >> 2)) * 16 + q * 4 + (j & 3);
            f[j] = (__bf16)W3[h * D_ + n];
        }
        w3f[kt] = f;
    }
    // biases along the C/D row axis (feature = ct*16 + q*4 + r)
    f32x4 b2r[8];
#pragma unroll
    for (int ct = 0; ct < 8; ++ct)
#pragma unroll
        for (int r = 0; r < 4; ++r) b2r[ct][r] = b2[ct * 16 + q * 4 + r];
    f32x4 b3r;
#pragma unroll
    for (int r = 0; r < 4; ++r) b3r[r] = b3[q * 4 + r];

    // ---- state: lane holds X[n][q*4 .. q*4+3] (transposed layout) ----
    f32x4 x = *(const f32x4*)&X0[gr * D_ + q * 4];
    float v = V0[gr];
    f32x2 y2 = *(const f32x2*)&Yobs[gr * P_ + q * 2];
    const __bf16 yb0 = (__bf16)y2[0], yb1 = (__bf16)y2[1];

    const float* npb = noise + (size_t)gr * D_ + q * 4;
    f32x4 e0 = *(const f32x4*)npb;                       // step 0
    f32x4 e1 = *(const f32x4*)(npb + (size_t)N_ * D_);   // step 1
    float t = 0.0f;

    for (int m = 0; m < M_; ++m) {
        // prefetch noise 2 steps ahead (clamped; redundant tail loads are free)
        int mp = (m + 2 < M_) ? (m + 2) : (M_ - 1);
        f32x4 e2 = *(const f32x4*)(npb + (size_t)mp * N_ * D_);

        // ---- layer 1: B fragment = [X(4) | Y(2) | one | t] per lane ----
        bf16x8 a0;
        a0[0] = (__bf16)x[0]; a0[1] = (__bf16)x[1];
        a0[2] = (__bf16)x[2]; a0[3] = (__bf16)x[3];
        a0[4] = yb0; a0[5] = yb1;
        a0[6] = (q == 0) ? (__bf16)1.0f : (__bf16)0.0f;
        a0[7] = (q == 0) ? (__bf16)t    : (__bf16)0.0f;

        f32x4 h1c[8];
#pragma unroll
        for (int ct = 0; ct < 8; ++ct)
            h1c[ct] = __builtin_amdgcn_mfma_f32_16x16x32_bf16(
                w1f[ct], a0, (f32x4){0.f, 0.f, 0.f, 0.f}, 0, 0, 0);

        // relu + cvt -> B fragments under pi (pure register shuffle-free)
        bf16x8 h1b[4];
#pragma unroll
        for (int kt = 0; kt < 4; ++kt) {
            bf16x8 f;
#pragma unroll
            for (int j = 0; j < 4; ++j) f[j]     = (__bf16)fmaxf(h1c[2 * kt][j], 0.0f);
#pragma unroll
            for (int j = 0; j < 4; ++j) f[4 + j] = (__bf16)fmaxf(h1c[2 * kt + 1][j], 0.0f);
            h1b[kt] = f;
        }

        // ---- layer 2: 8 independent chains of 4 MFMAs ----
        f32x4 h2c[8];
#pragma unroll
        for (int ct = 0; ct < 8; ++ct) {
            f32x4 c = b2r[ct];
#pragma unroll
            for (int kt = 0; kt < 4; ++kt)
                c = __builtin_amdgcn_mfma_f32_16x16x32_bf16(w2f[ct][kt], h1b[kt], c, 0, 0, 0);
            h2c[ct] = c;
        }
        bf16x8 h2b[4];
#pragma unroll
        for (int kt = 0; kt < 4; ++kt) {
            bf16x8 f;
#pragma unroll
            for (int j = 0; j < 4; ++j) f[j]     = (__bf16)fmaxf(h2c[2 * kt][j], 0.0f);
#pragma unroll
            for (int j = 0; j < 4; ++j) f[4 + j] = (__bf16)fmaxf(h2c[2 * kt + 1][j], 0.0f);
            h2b[kt] = f;
        }

        // ---- layer 3: two parallel 2-chains ----
        f32x4 za = __builtin_amdgcn_mfma_f32_16x16x32_bf16(w3f[0], h2b[0], b3r, 0, 0, 0);
        za = __builtin_amdgcn_mfma_f32_16x16x32_bf16(w3f[1], h2b[1], za, 0, 0, 0);
        f32x4 zb = __builtin_amdgcn_mfma_f32_16x16x32_bf16(
            w3f[2], h2b[2], (f32x4){0.f, 0.f, 0.f, 0.f}, 0, 0, 0);
        zb = __builtin_amdgcn_mfma_f32_16x16x32_bf16(w3f[3], h2b[3], zb, 0, 0, 0);

        // ---- V, X update (lane holds Z[n][q*4+r], r=0..3) ----
        float part = 0.0f;
#pragma unroll
        for (int r = 0; r < 4; ++r) {
            float z  = za[r] + zb[r];
            float wn = sqdt * e0[r];
            part += z * wn + 0.5f * dt * z * z;
            x[r] = x[r] * (1.0f - dt) + wn;
        }
        part += __shfl_xor(part, 16);
        part += __shfl_xor(part, 32);
        v += part;

        e0 = e1; e1 = e2;
        t += dt;
    }

    // ---- store: X (N x 16) then V (N) ----
    *(f32x4*)&out[gr * D_ + q * 4] = x;
    if (q == 0) out[N_ * D_ + gr] = v;
}

extern "C" void kernel_launch(void* const* d_in, const int* in_sizes, int n_in,
                              void* d_out, int out_size, void* d_ws, size_t ws_size,
                              hipStream_t stream)
{
    const float* X0 = (const float*)d_in[0];
    const float* V0 = (const float*)d_in[1];
    const float* Y  = (const float*)d_in[2];
    const float* nz = (const float*)d_in[3];
    const float* W1 = (const float*)d_in[4];
    const float* b1 = (const float*)d_in[5];
    const float* W2 = (const float*)d_in[6];
    const float* b2 = (const float*)d_in[7];
    const float* W3 = (const float*)d_in[8];
    const float* b3 = (const float*)d_in[9];
    float* out = (float*)d_out;

    sde_fused<<<N_ / 16, 64, 0, stream>>>(X0, V0, Y, nz, W1, b1, W2, b2, W3, b3, out);
}

// Round 3
// 138.078 us; speedup vs baseline: 1.3768x; 1.0292x over previous
//
#include <hip/hip_runtime.h>

typedef __bf16   bf16x8 __attribute__((ext_vector_type(8)));
typedef float    f32x4  __attribute__((ext_vector_type(4)));
typedef float    f32x2  __attribute__((ext_vector_type(2)));
typedef uint32_t u32x4  __attribute__((ext_vector_type(4)));

constexpr int N_ = 16384;
constexpr int D_ = 16;
constexpr int P_ = 8;
constexpr int H_ = 128;
constexpr int M_ = 50;

// pack two f32 -> one bf16x2 register word (round-half-up; 3 VALU ops)
__device__ __forceinline__ uint32_t pk_bf16(float a, float b) {
    uint32_t ua = __builtin_bit_cast(uint32_t, a) + 0x8000u;
    uint32_t ub = __builtin_bit_cast(uint32_t, b) + 0x8000u;
    return __builtin_amdgcn_perm(ub, ua, 0x07060302u);   // [a.hi16 | b.hi16]
}
__device__ __forceinline__ uint32_t pk_relu_bf16(float a, float b) {
    return pk_bf16(fmaxf(a, 0.0f), fmaxf(b, 0.0f));
}

// Transposed register-resident formulation (see R2): h^T = W^T @ act^T, each
// layer's C/D output is the next layer's B operand under the contraction
// permutation pi(kt,q,j) = (kt*2+(j>>2))*16 + q*4 + (j&3) baked into the
// register-resident weight fragments. Zero LDS / zero barriers in the loop.
// R3: bf16x8 fragments assembled as u32x4 via v_perm packed conversion
// (no sub-register inserts), V-reduction deferred to after the loop.
__global__ __launch_bounds__(64, 1)
void sde_fused(const float* __restrict__ X0,
               const float* __restrict__ V0,
               const float* __restrict__ Yobs,
               const float* __restrict__ noise,
               const float* __restrict__ W1, const float* __restrict__ b1,
               const float* __restrict__ W2, const float* __restrict__ b2,
               const float* __restrict__ W3, const float* __restrict__ b3,
               float* __restrict__ out)
{
    const int lane = threadIdx.x;
    const int n    = lane & 15;
    const int q    = lane >> 4;
    const int gr   = blockIdx.x * 16 + n;

    const float dt   = 0.02f;
    const float sqdt = 0.1414213562373095f;

    // ---- weight fragments, A-operand layout A[m=lane&15][k=q*8+j] ----
    bf16x8 w1f[8];
#pragma unroll
    for (int ct = 0; ct < 8; ++ct) {
        u32x4 u;
        u[0] = pk_bf16(W1[(1 + q * 4 + 0) * H_ + ct * 16 + n],
                       W1[(1 + q * 4 + 1) * H_ + ct * 16 + n]);
        u[1] = pk_bf16(W1[(1 + q * 4 + 2) * H_ + ct * 16 + n],
                       W1[(1 + q * 4 + 3) * H_ + ct * 16 + n]);
        u[2] = pk_bf16(W1[(17 + q * 2 + 0) * H_ + ct * 16 + n],
                       W1[(17 + q * 2 + 1) * H_ + ct * 16 + n]);
        u[3] = (q == 0) ? pk_bf16(b1[ct * 16 + n], W1[ct * 16 + n]) : 0u;
        w1f[ct] = __builtin_bit_cast(bf16x8, u);
    }
    bf16x8 w2f[8][4];
#pragma unroll
    for (int ct = 0; ct < 8; ++ct)
#pragma unroll
        for (int kt = 0; kt < 4; ++kt) {
            u32x4 u;
#pragma unroll
            for (int w = 0; w < 4; ++w) {
                int h0 = (kt * 2 + (w >> 1)) * 16 + q * 4 + (w & 1) * 2;
                u[w] = pk_bf16(W2[h0 * H_ + ct * 16 + n],
                               W2[(h0 + 1) * H_ + ct * 16 + n]);
            }
            w2f[ct][kt] = __builtin_bit_cast(bf16x8, u);
        }
    bf16x8 w3f[4];
#pragma unroll
    for (int kt = 0; kt < 4; ++kt) {
        u32x4 u;
#pragma unroll
        for (int w = 0; w < 4; ++w) {
            int h0 = (kt * 2 + (w >> 1)) * 16 + q * 4 + (w & 1) * 2;
            u[w] = pk_bf16(W3[h0 * D_ + n], W3[(h0 + 1) * D_ + n]);
        }
        w3f[kt] = __builtin_bit_cast(bf16x8, u);
    }
    f32x4 b2r[8];
#pragma unroll
    for (int ct = 0; ct < 8; ++ct)
#pragma unroll
        for (int r = 0; r < 4; ++r) b2r[ct][r] = b2[ct * 16 + q * 4 + r];
    f32x4 b3r;
#pragma unroll
    for (int r = 0; r < 4; ++r) b3r[r] = b3[q * 4 + r];

    // ---- state ----
    f32x4 x = *(const f32x4*)&X0[gr * D_ + q * 4];
    f32x2 y2 = *(const f32x2*)&Yobs[gr * P_ + q * 2];
    const uint32_t yw = pk_bf16(y2[0], y2[1]);   // constant word2 of a0

    const float* npb = noise + (size_t)gr * D_ + q * 4;
    f32x4 e0 = *(const f32x4*)npb;
    f32x4 e1 = *(const f32x4*)(npb + (size_t)N_ * D_);
    float t = 0.0f;
    float vacc = 0.0f;   // per-lane V partial, reduced once after the loop

    for (int m = 0; m < M_; ++m) {
        int mp = (m + 2 < M_) ? (m + 2) : (M_ - 1);
        f32x4 e2 = *(const f32x4*)(npb + (size_t)mp * N_ * D_);

        // ---- layer 1 B fragment: [X(4) | Y(2) | one | t] ----
        u32x4 au;
        au[0] = pk_bf16(x[0], x[1]);
        au[1] = pk_bf16(x[2], x[3]);
        au[2] = yw;
        au[3] = (q == 0) ? pk_bf16(1.0f, t) : 0u;
        bf16x8 a0 = __builtin_bit_cast(bf16x8, au);

        f32x4 h1c[8];
#pragma unroll
        for (int ct = 0; ct < 8; ++ct)
            h1c[ct] = __builtin_amdgcn_mfma_f32_16x16x32_bf16(
                w1f[ct], a0, (f32x4){0.f, 0.f, 0.f, 0.f}, 0, 0, 0);

        bf16x8 h1b[4];
#pragma unroll
        for (int kt = 0; kt < 4; ++kt) {
            u32x4 u;
            u[0] = pk_relu_bf16(h1c[2 * kt][0], h1c[2 * kt][1]);
            u[1] = pk_relu_bf16(h1c[2 * kt][2], h1c[2 * kt][3]);
            u[2] = pk_relu_bf16(h1c[2 * kt + 1][0], h1c[2 * kt + 1][1]);
            u[3] = pk_relu_bf16(h1c[2 * kt + 1][2], h1c[2 * kt + 1][3]);
            h1b[kt] = __builtin_bit_cast(bf16x8, u);
        }

        // ---- layer 2: 8 independent chains of 4 ----
        f32x4 h2c[8];
#pragma unroll
        for (int ct = 0; ct < 8; ++ct) {
            f32x4 c = b2r[ct];
#pragma unroll
            for (int kt = 0; kt < 4; ++kt)
                c = __builtin_amdgcn_mfma_f32_16x16x32_bf16(w2f[ct][kt], h1b[kt], c, 0, 0, 0);
            h2c[ct] = c;
        }
        bf16x8 h2b[4];
#pragma unroll
        for (int kt = 0; kt < 4; ++kt) {
            u32x4 u;
            u[0] = pk_relu_bf16(h2c[2 * kt][0], h2c[2 * kt][1]);
            u[1] = pk_relu_bf16(h2c[2 * kt][2], h2c[2 * kt][3]);
            u[2] = pk_relu_bf16(h2c[2 * kt + 1][0], h2c[2 * kt + 1][1]);
            u[3] = pk_relu_bf16(h2c[2 * kt + 1][2], h2c[2 * kt + 1][3]);
            h2b[kt] = __builtin_bit_cast(bf16x8, u);
        }

        // ---- layer 3: two parallel 2-chains ----
        f32x4 za = __builtin_amdgcn_mfma_f32_16x16x32_bf16(w3f[0], h2b[0], b3r, 0, 0, 0);
        za = __builtin_amdgcn_mfma_f32_16x16x32_bf16(w3f[1], h2b[1], za, 0, 0, 0);
        f32x4 zb = __builtin_amdgcn_mfma_f32_16x16x32_bf16(
            w3f[2], h2b[2], (f32x4){0.f, 0.f, 0.f, 0.f}, 0, 0, 0);
        zb = __builtin_amdgcn_mfma_f32_16x16x32_bf16(w3f[3], h2b[3], zb, 0, 0, 0);

        // ---- V partial + X update (no cross-lane work in the loop) ----
#pragma unroll
        for (int r = 0; r < 4; ++r) {
            float z  = za[r] + zb[r];
            float wn = sqdt * e0[r];
            vacc = fmaf(z, wn, fmaf(0.01f * z, z, vacc));   // z*wn + dt/2*z^2
            x[r] = fmaf(x[r], 0.98f, wn);                   // (1-dt)*x + wn
        }

        e0 = e1; e1 = e2;
        t += dt;
    }

    // ---- final V reduction across the 4 q-groups ----
    float part = vacc;
    part += __shfl_xor(part, 16);
    part += __shfl_xor(part, 32);
    float v = V0[gr] + part;

    *(f32x4*)&out[gr * D_ + q * 4] = x;
    if (q == 0) out[N_ * D_ + gr] = v;
}

extern "C" void kernel_launch(void* const* d_in, const int* in_sizes, int n_in,
                              void* d_out, int out_size, void* d_ws, size_t ws_size,
                              hipStream_t stream)
{
    const float* X0 = (const float*)d_in[0];
    const float* V0 = (const float*)d_in[1];
    const float* Y  = (const float*)d_in[2];
    const float* nz = (const float*)d_in[3];
    const float* W1 = (const float*)d_in[4];
    const float* b1 = (const float*)d_in[5];
    const float* W2 = (const float*)d_in[6];
    const float* b2 = (const float*)d_in[7];
    const float* W3 = (const float*)d_in[8];
    const float* b3 = (const float*)d_in[9];
    float* out = (float*)d_out;

    sde_fused<<<N_ / 16, 64, 0, stream>>>(X0, V0, Y, nz, W1, b1, W2, b2, W3, b3, out);
}